// Round 10
// baseline (370.077 us; speedup 1.0000x reference)
//
#include <hip/hip_runtime.h>
#include <hip/hip_bf16.h>

// Problem: B=2,S=8192 -> TOK=16384 tokens; H=1024; DFF=4096.
// out[t] = mask[t] ? relu((h[t]*w[t]) @ W1 + b1) @ W2 + b2 : 0
// R14: gemm2 re-waved: same 64x128 block tile / 24 KiB LDS / 1144-block
//     grid, but 2 waves x (64x64 out) instead of 4 x (32x64). Per-K-step
//     LDS read 48->32 KiB (gap to MFMA 1.86x -> 1.21x, = gemm1's ratio)
//     staying in the conflict-free 16x16 fragment class (R12's 32x32 class
//     is 4-way conflicted). Cost: half the waves (TLP) — bet is LDS
//     throughput, not latency, binds (R10 arithmetic). Rest = R13 (best).

#define TOK 16384
#define HID 1024
#define FF  4096

typedef __attribute__((ext_vector_type(8))) __bf16 bf16x8;
typedef __attribute__((ext_vector_type(4))) float f32x4;

__device__ __forceinline__ void gload_lds16(const void* g, void* l) {
  // async global->LDS, 16B per lane; LDS dest = wave-uniform base + lane*16
  __builtin_amdgcn_global_load_lds((const __attribute__((address_space(1))) void*)g,
                                   (__attribute__((address_space(3))) void*)l, 16, 0, 0);
}

// ---------------- k_pre: W1^T + gate+compact (one dispatch) ----------------
// Blocks [0,1024): transpose W1 (64x64 tiles); [1024,2048): gate 16 tok/blk.
#define GTOK 16
#define NBT1 1024  // (FF/64)*(HID/64)

__global__ __launch_bounds__(256) void k_pre(const float* __restrict__ W1,
                                             __hip_bfloat16* __restrict__ W1t,
                                             const float* __restrict__ h,
                                             const float* __restrict__ wg,
                                             const float* __restrict__ bgp,
                                             const int* __restrict__ labels,
                                             float* __restrict__ out,
                                             __hip_bfloat16* __restrict__ A,
                                             int* __restrict__ idx,
                                             int* __restrict__ cnt) {
  const int bid = blockIdx.x;
  const int tid = threadIdx.x;

  if (bid < NBT1) {
    // -------- transpose W1[HID][FF] fp32 -> W1t[FF][HID] bf16 --------
    const int nbc = FF / 64;
    const int c0 = (bid % nbc) * 64, r0 = (bid / nbc) * 64;
    __shared__ float tile[64][65];        // stride 65: conflict-free col reads
    const int tx = tid & 63, ty = tid >> 6;
#pragma unroll
    for (int i = 0; i < 16; ++i)
      tile[ty + i * 4][tx] = W1[(size_t)(r0 + ty + i * 4) * FF + (c0 + tx)];
    __syncthreads();
#pragma unroll
    for (int i = 0; i < 16; ++i)
      W1t[(size_t)(c0 + ty + i * 4) * HID + (r0 + tx)] =
          __float2bfloat16(tile[tx][ty + i * 4]);
    return;
  }

  // -------- gate + compact + zero dropped rows --------
  const int gb = bid - NBT1;
  const int t0 = gb * GTOK;
  const int wave = tid >> 6, lane = tid & 63;

  float4 gv[4];
#pragma unroll
  for (int it = 0; it < 4; ++it) gv[it] = ((const float4*)wg)[it * 64 + lane];

  // hold h rows in registers across both passes (64 VGPR)
  float4 hv[4][4];
  __shared__ float slogit[GTOK];
  __shared__ int sslot[GTOK];

#pragma unroll
  for (int r = 0; r < 4; ++r) {
    const int li = r * 4 + wave;
    const float* hrow = h + (size_t)(t0 + li) * HID;
    float d = 0.f;
#pragma unroll
    for (int it = 0; it < 4; ++it) {
      hv[r][it] = ((const float4*)hrow)[it * 64 + lane];
      d += hv[r][it].x * gv[it].x + hv[r][it].y * gv[it].y +
           hv[r][it].z * gv[it].z + hv[r][it].w * gv[it].w;
    }
#pragma unroll
    for (int o = 32; o > 0; o >>= 1) d += __shfl_down(d, o, 64);
    if (lane == 0) slogit[li] = d;
  }
  __syncthreads();

  if (tid == 0) {  // prefix over 16 keep flags; ONE atomic per block
    const float bg = bgp[0];
    int slots[GTOK];
    int n = 0;
#pragma unroll
    for (int li = 0; li < GTOK; ++li) {
      const bool keep = (slogit[li] + bg >= 0.0f) || (labels[t0 + li] == -100);
      slots[li] = keep ? n++ : -1;
    }
    const int base = atomicAdd(cnt, n);
#pragma unroll
    for (int li = 0; li < GTOK; ++li)
      sslot[li] = slots[li] >= 0 ? base + slots[li] : -1;
  }
  __syncthreads();

#pragma unroll
  for (int r = 0; r < 4; ++r) {
    const int li = r * 4 + wave;
    const int t = t0 + li;
    const int m = sslot[li];
    if (m >= 0) {
      if (lane == 0) idx[m] = t;
      const float logit = slogit[li] + bgp[0];
      const float w = 1.0f / (1.0f + __expf(-logit));
#pragma unroll
      for (int it = 0; it < 4; ++it) {
        union { ushort4 u; __hip_bfloat16 b[4]; } pk;
        pk.b[0] = __float2bfloat16(hv[r][it].x * w);
        pk.b[1] = __float2bfloat16(hv[r][it].y * w);
        pk.b[2] = __float2bfloat16(hv[r][it].z * w);
        pk.b[3] = __float2bfloat16(hv[r][it].w * w);
        ((ushort4*)(A + (size_t)m * HID))[it * 64 + lane] = pk.u;
      }
    } else {
      const float4 z = make_float4(0.f, 0.f, 0.f, 0.f);
#pragma unroll
      for (int it = 0; it < 4; ++it)
        ((float4*)(out + (size_t)t * HID))[it * 64 + lane] = z;
    }
  }
}

// ---------------- GEMM LDS swizzle (both GEMMs) ----------------
// LDS rows of 64 k-elems (128 B). Staging: lane l covers row
// r = wbase + c*8 + (l>>3), source chunk g = (l&7) ^ (r&7), stored at
// position l&7. Read of chunk ck of row r at position ck ^ (r&7); fragment
// reads touch 16 rows x 4 chunks per instruction -> 2-way bank aliasing
// only (free; measured 0 conflicts). NOTE: 32x32 MFMA layout (32 rows x
// 2 chunks) is 4-way conflicted in this scheme — do not use (R12).

// GEMM1 dispatch: blocks [0,1024) transpose W2[FF][HID]->W2t[HID][FF]
// (overlaps with gemm compute; W2t only needed by gemm2); blocks
// [1024,5120) = 128x128-tile GEMM, single-buffered (R6-proven, ~9
// active blocks/CU -> cross-block latency hiding).
#define NBT2 1024  // (HID/64)*(FF/64)

__global__ __launch_bounds__(256, 2) void k_gemm1(const __hip_bfloat16* __restrict__ A,
                                                  const __hip_bfloat16* __restrict__ Bt,
                                                  const float* __restrict__ bias,
                                                  __hip_bfloat16* __restrict__ Act,
                                                  const int* __restrict__ cnt,
                                                  const float* __restrict__ W2,
                                                  __hip_bfloat16* __restrict__ W2t) {
  __shared__ char smem[32768];           // union: gemm lA|lB, transpose tile
  const int bid = blockIdx.x;
  const int tid = threadIdx.x;

  if (bid < NBT2) {
    // -------- transpose W2[FF][HID] fp32 -> W2t[HID][FF] bf16 --------
    float (*tile)[65] = (float(*)[65])smem;   // 64x65 fp32 = 16.25 KiB
    const int nbc = HID / 64;
    const int c0 = (bid % nbc) * 64, r0 = (bid / nbc) * 64;
    const int tx = tid & 63, ty = tid >> 6;
#pragma unroll
    for (int i = 0; i < 16; ++i)
      tile[ty + i * 4][tx] = W2[(size_t)(r0 + ty + i * 4) * HID + (c0 + tx)];
    __syncthreads();
#pragma unroll
    for (int i = 0; i < 16; ++i)
      W2t[(size_t)(c0 + ty + i * 4) * FF + (r0 + tx)] =
          __float2bfloat16(tile[tx][ty + i * 4]);
    return;
  }

  const int g = bid - NBT2;
  const int Mc = *cnt;
  const int m0 = (g & 127) * 128;        // m-fast: consecutive blocks share B panel
  if (m0 >= Mc) return;
  const int n0 = (g >> 7) * 128;

  __hip_bfloat16* lA = (__hip_bfloat16*)smem;            // 16 KiB
  __hip_bfloat16* lB = (__hip_bfloat16*)(smem + 16384);  // 16 KiB

  const int wave = tid >> 6, lane = tid & 63;
  const int wr = (wave >> 1) * 64, wc = (wave & 1) * 64;
  const int fm = lane & 15, quad = lane >> 4;

  const int srow = (lane >> 3);                       // 0..7
  const int sg   = ((lane & 7) ^ srow) * 8;           // global elem offset

  f32x4 acc[4][4] = {};

  const __hip_bfloat16* gA = A  + (size_t)(m0 + wave * 32 + srow) * HID + sg;
  const __hip_bfloat16* gB = Bt + (size_t)(n0 + wave * 32 + srow) * HID + sg;
  char* dA = (char*)lA + wave * 4096;
  char* dB = (char*)lB + wave * 4096;

  for (int kt = 0; kt < HID; kt += 64) {
    __syncthreads();
#pragma unroll
    for (int c = 0; c < 4; ++c) {
      gload_lds16(gA + (size_t)(c * 8) * HID + kt, dA + c * 1024);
      gload_lds16(gB + (size_t)(c * 8) * HID + kt, dB + c * 1024);
    }
    __syncthreads();
#pragma unroll
    for (int ks = 0; ks < 2; ++ks) {
      bf16x8 af[4], bb[4];
#pragma unroll
      for (int i = 0; i < 4; ++i)
        af[i] = *(const bf16x8*)&lA[(wr + i * 16 + fm) * 64 + (((ks * 4 + quad) ^ (fm & 7)) * 8)];
#pragma unroll
      for (int j = 0; j < 4; ++j)
        bb[j] = *(const bf16x8*)&lB[(wc + j * 16 + fm) * 64 + (((ks * 4 + quad) ^ (fm & 7)) * 8)];
#pragma unroll
      for (int i = 0; i < 4; ++i)
#pragma unroll
        for (int j = 0; j < 4; ++j)
          acc[i][j] = __builtin_amdgcn_mfma_f32_16x16x32_bf16(af[i], bb[j], acc[i][j], 0, 0, 0);
    }
  }

#pragma unroll
  for (int j = 0; j < 4; ++j) {
    const int col = n0 + wc + j * 16 + fm;
    const float bv = bias[col];
#pragma unroll
    for (int i = 0; i < 4; ++i) {
      const int rbase = m0 + wr + i * 16 + quad * 4;
#pragma unroll
      for (int r = 0; r < 4; ++r) {
        float v = acc[i][j][r] + bv;
        v = v > 0.f ? v : 0.f;
        Act[(size_t)(rbase + r) * FF + col] = __float2bfloat16(v);
      }
    }
  }
}

// GEMM2: out[idx[m]] = Act @ W2t^T + b2, fp32 scatter. K=FF=4096.
// BM=64 x BN=128 block tile (1144 active blocks, 24 KiB LDS — R6-proven
// grid), but 2 waves x (64x64 out), acc[4][4]/wave. Per-K-step LDS read
// 32 KiB vs 310-cyc MFMA (ratio 1.21, = gemm1). 128-thread blocks.
__global__ __launch_bounds__(128, 3) void k_gemm2(const __hip_bfloat16* __restrict__ Act,
                                                  const __hip_bfloat16* __restrict__ Bt,
                                                  const float* __restrict__ bias,
                                                  const int* __restrict__ idx,
                                                  float* __restrict__ out,
                                                  const int* __restrict__ cnt) {
  const int Mc = *cnt;
  const int m0 = blockIdx.x * 64;
  if (m0 >= Mc) return;
  const int n0 = blockIdx.y * 128;

  __shared__ __hip_bfloat16 lA[64 * 64];   // 8 KiB
  __shared__ __hip_bfloat16 lB[128 * 64];  // 16 KiB

  const int tid = threadIdx.x;
  const int wave = tid >> 6, lane = tid & 63;   // wave 0..1
  const int fm = lane & 15, quad = lane >> 4;
  const int srow = (lane >> 3);
  const int sg   = ((lane & 7) ^ srow) * 8;

  f32x4 acc[4][4] = {};

  // staging: wave w stages A rows [w*32,+32) (4 calls) + B rows [w*64,+64) (8 calls)
  const __hip_bfloat16* gA = Act + (size_t)(m0 + wave * 32 + srow) * FF + sg;
  const __hip_bfloat16* gB = Bt  + (size_t)(n0 + wave * 64 + srow) * FF + sg;
  char* dA = (char*)lA + wave * 4096;
  char* dB = (char*)lB + wave * 8192;

  for (int kt = 0; kt < FF; kt += 64) {
    __syncthreads();
#pragma unroll
    for (int c = 0; c < 4; ++c)
      gload_lds16(gA + (size_t)(c * 8) * FF + kt, dA + c * 1024);
#pragma unroll
    for (int c = 0; c < 8; ++c)
      gload_lds16(gB + (size_t)(c * 8) * FF + kt, dB + c * 1024);
    __syncthreads();
#pragma unroll
    for (int ks = 0; ks < 2; ++ks) {
      bf16x8 af[4], bb[4];
#pragma unroll
      for (int i = 0; i < 4; ++i)
        af[i] = *(const bf16x8*)&lA[(i * 16 + fm) * 64 + (((ks * 4 + quad) ^ (fm & 7)) * 8)];
#pragma unroll
      for (int j = 0; j < 4; ++j)
        bb[j] = *(const bf16x8*)&lB[(wave * 64 + j * 16 + fm) * 64 + (((ks * 4 + quad) ^ (fm & 7)) * 8)];
#pragma unroll
      for (int i = 0; i < 4; ++i)
#pragma unroll
        for (int j = 0; j < 4; ++j)
          acc[i][j] = __builtin_amdgcn_mfma_f32_16x16x32_bf16(af[i], bb[j], acc[i][j], 0, 0, 0);
    }
  }

#pragma unroll
  for (int i = 0; i < 4; ++i) {
#pragma unroll
    for (int r = 0; r < 4; ++r) {
      const int m = m0 + i * 16 + quad * 4 + r;
      if (m < Mc) {
        const int t = idx[m];
        float* orow = out + (size_t)t * HID + n0 + wave * 64 + fm;
#pragma unroll
        for (int j = 0; j < 4; ++j)
          orow[j * 16] = acc[i][j][r] + bias[n0 + wave * 64 + j * 16 + fm];
      }
    }
  }
}

// ---------------- launch ----------------
extern "C" void kernel_launch(void* const* d_in, const int* in_sizes, int n_in,
                              void* d_out, int out_size, void* d_ws, size_t ws_size,
                              hipStream_t stream) {
  const float* h   = (const float*)d_in[0];
  const float* Wg  = (const float*)d_in[3];
  const float* bg  = (const float*)d_in[4];
  const float* W1  = (const float*)d_in[5];
  const float* b1  = (const float*)d_in[6];
  const float* W2  = (const float*)d_in[7];
  const float* b2  = (const float*)d_in[8];
  const int*  labels = (const int*)d_in[9];
  float* out = (float*)d_out;

  char* ws = (char*)d_ws;
  int* cnt            = (int*)(ws + 0);
  int* idx            = (int*)(ws + 1024);
  __hip_bfloat16* W1t = (__hip_bfloat16*)(ws + (1u  << 17));   // [FF][HID]
  __hip_bfloat16* W2t = (__hip_bfloat16*)(ws + (16u << 20));   // [HID][FF]
  __hip_bfloat16* A   = (__hip_bfloat16*)(ws + (32u << 20));   // [TOK][HID]
  __hip_bfloat16* Act = (__hip_bfloat16*)(ws + (64ull << 20)); // [TOK][FF]

  hipMemsetAsync(cnt, 0, 4, stream);
  k_pre<<<NBT1 + TOK / GTOK, 256, 0, stream>>>(W1, W1t, h, Wg, bg, labels,
                                               out, A, idx, cnt);
  k_gemm1<<<NBT2 + (TOK / 128) * (FF / 128), 256, 0, stream>>>(A, W1t, b1, Act,
                                                               cnt, W2, W2t);
  k_gemm2<<<dim3(TOK / 64, HID / 128), 128, 0, stream>>>(Act, W2t, b2, idx, out, cnt);
}

// Round 11
// 362.643 us; speedup vs baseline: 1.0205x; 1.0205x over previous
//
#include <hip/hip_runtime.h>
#include <hip/hip_bf16.h>

// Problem: B=2,S=8192 -> TOK=16384 tokens; H=1024; DFF=4096.
// out[t] = mask[t] ? relu((h[t]*w[t]) @ W1 + b1) @ W2 + b2 : 0
// R15: gemm2 2-wave REVERTED (R14: 105->118, MfmaUtil down — gemm2 is
//     TLP-limited at 4.5 active blocks/CU; 7 variants measured, R6's
//     4-wave 64x128 single-buffer is the plateau). gemm2 = R6-exact.
//     NEW (T1): gemm1 gemm blocks XCD-chunk-swizzled — XCD x only gets
//     m-tiles ≡ x (mod 8), so each XCD's A working set (16 strided tiles,
//     ~2.3MB active) + W1t panel fits its 4MB L2 and all 32 A re-reads
//     (one per n-panel) become local-L2 hits instead of L3 round trips.
//     Bijective remap only; no structural change. Rest = R13 (best, 365.5).

#define TOK 16384
#define HID 1024
#define FF  4096

typedef __attribute__((ext_vector_type(8))) __bf16 bf16x8;
typedef __attribute__((ext_vector_type(4))) float f32x4;

__device__ __forceinline__ void gload_lds16(const void* g, void* l) {
  // async global->LDS, 16B per lane; LDS dest = wave-uniform base + lane*16
  __builtin_amdgcn_global_load_lds((const __attribute__((address_space(1))) void*)g,
                                   (__attribute__((address_space(3))) void*)l, 16, 0, 0);
}

// ---------------- k_pre: W1^T + gate+compact (one dispatch) ----------------
// Blocks [0,1024): transpose W1 (64x64 tiles); [1024,2048): gate 16 tok/blk.
#define GTOK 16
#define NBT1 1024  // (FF/64)*(HID/64)

__global__ __launch_bounds__(256) void k_pre(const float* __restrict__ W1,
                                             __hip_bfloat16* __restrict__ W1t,
                                             const float* __restrict__ h,
                                             const float* __restrict__ wg,
                                             const float* __restrict__ bgp,
                                             const int* __restrict__ labels,
                                             float* __restrict__ out,
                                             __hip_bfloat16* __restrict__ A,
                                             int* __restrict__ idx,
                                             int* __restrict__ cnt) {
  const int bid = blockIdx.x;
  const int tid = threadIdx.x;

  if (bid < NBT1) {
    // -------- transpose W1[HID][FF] fp32 -> W1t[FF][HID] bf16 --------
    const int nbc = FF / 64;
    const int c0 = (bid % nbc) * 64, r0 = (bid / nbc) * 64;
    __shared__ float tile[64][65];        // stride 65: conflict-free col reads
    const int tx = tid & 63, ty = tid >> 6;
#pragma unroll
    for (int i = 0; i < 16; ++i)
      tile[ty + i * 4][tx] = W1[(size_t)(r0 + ty + i * 4) * FF + (c0 + tx)];
    __syncthreads();
#pragma unroll
    for (int i = 0; i < 16; ++i)
      W1t[(size_t)(c0 + ty + i * 4) * HID + (r0 + tx)] =
          __float2bfloat16(tile[tx][ty + i * 4]);
    return;
  }

  // -------- gate + compact + zero dropped rows --------
  const int gb = bid - NBT1;
  const int t0 = gb * GTOK;
  const int wave = tid >> 6, lane = tid & 63;

  float4 gv[4];
#pragma unroll
  for (int it = 0; it < 4; ++it) gv[it] = ((const float4*)wg)[it * 64 + lane];

  // hold h rows in registers across both passes (64 VGPR)
  float4 hv[4][4];
  __shared__ float slogit[GTOK];
  __shared__ int sslot[GTOK];

#pragma unroll
  for (int r = 0; r < 4; ++r) {
    const int li = r * 4 + wave;
    const float* hrow = h + (size_t)(t0 + li) * HID;
    float d = 0.f;
#pragma unroll
    for (int it = 0; it < 4; ++it) {
      hv[r][it] = ((const float4*)hrow)[it * 64 + lane];
      d += hv[r][it].x * gv[it].x + hv[r][it].y * gv[it].y +
           hv[r][it].z * gv[it].z + hv[r][it].w * gv[it].w;
    }
#pragma unroll
    for (int o = 32; o > 0; o >>= 1) d += __shfl_down(d, o, 64);
    if (lane == 0) slogit[li] = d;
  }
  __syncthreads();

  if (tid == 0) {  // prefix over 16 keep flags; ONE atomic per block
    const float bg = bgp[0];
    int slots[GTOK];
    int n = 0;
#pragma unroll
    for (int li = 0; li < GTOK; ++li) {
      const bool keep = (slogit[li] + bg >= 0.0f) || (labels[t0 + li] == -100);
      slots[li] = keep ? n++ : -1;
    }
    const int base = atomicAdd(cnt, n);
#pragma unroll
    for (int li = 0; li < GTOK; ++li)
      sslot[li] = slots[li] >= 0 ? base + slots[li] : -1;
  }
  __syncthreads();

#pragma unroll
  for (int r = 0; r < 4; ++r) {
    const int li = r * 4 + wave;
    const int t = t0 + li;
    const int m = sslot[li];
    if (m >= 0) {
      if (lane == 0) idx[m] = t;
      const float logit = slogit[li] + bgp[0];
      const float w = 1.0f / (1.0f + __expf(-logit));
#pragma unroll
      for (int it = 0; it < 4; ++it) {
        union { ushort4 u; __hip_bfloat16 b[4]; } pk;
        pk.b[0] = __float2bfloat16(hv[r][it].x * w);
        pk.b[1] = __float2bfloat16(hv[r][it].y * w);
        pk.b[2] = __float2bfloat16(hv[r][it].z * w);
        pk.b[3] = __float2bfloat16(hv[r][it].w * w);
        ((ushort4*)(A + (size_t)m * HID))[it * 64 + lane] = pk.u;
      }
    } else {
      const float4 z = make_float4(0.f, 0.f, 0.f, 0.f);
#pragma unroll
      for (int it = 0; it < 4; ++it)
        ((float4*)(out + (size_t)t * HID))[it * 64 + lane] = z;
    }
  }
}

// ---------------- GEMM LDS swizzle (both GEMMs) ----------------
// LDS rows of 64 k-elems (128 B). Staging: lane l covers row
// r = wbase + c*8 + (l>>3), source chunk g = (l&7) ^ (r&7), stored at
// position l&7. Read of chunk ck of row r at position ck ^ (r&7); fragment
// reads touch 16 rows x 4 chunks per instruction -> 2-way bank aliasing
// only (free; measured 0 conflicts). NOTE: 32x32 MFMA layout (32 rows x
// 2 chunks) is 4-way conflicted in this scheme — do not use (R12).

// GEMM1 dispatch: blocks [0,1024) transpose W2[FF][HID]->W2t[HID][FF]
// (overlaps with gemm compute; W2t only needed by gemm2); blocks
// [1024,5120) = 128x128-tile GEMM, single-buffered, XCD-chunk-swizzled:
// g%8 = XCD; XCD x gets m-tiles {x, 8+x, 16+x, ...} (strided -> active
// tiles balanced) x all 32 n-panels; per-XCD A slice ~2.3MB active + W1t
// panel 256KB fits the 4MB XCD L2 -> A re-reads (32x) hit local L2.
#define NBT2 1024  // (HID/64)*(FF/64)

__global__ __launch_bounds__(256, 2) void k_gemm1(const __hip_bfloat16* __restrict__ A,
                                                  const __hip_bfloat16* __restrict__ Bt,
                                                  const float* __restrict__ bias,
                                                  __hip_bfloat16* __restrict__ Act,
                                                  const int* __restrict__ cnt,
                                                  const float* __restrict__ W2,
                                                  __hip_bfloat16* __restrict__ W2t) {
  __shared__ char smem[32768];           // union: gemm lA|lB, transpose tile
  const int bid = blockIdx.x;
  const int tid = threadIdx.x;

  if (bid < NBT2) {
    // -------- transpose W2[FF][HID] fp32 -> W2t[HID][FF] bf16 --------
    float (*tile)[65] = (float(*)[65])smem;   // 64x65 fp32 = 16.25 KiB
    const int nbc = HID / 64;
    const int c0 = (bid % nbc) * 64, r0 = (bid / nbc) * 64;
    const int tx = tid & 63, ty = tid >> 6;
#pragma unroll
    for (int i = 0; i < 16; ++i)
      tile[ty + i * 4][tx] = W2[(size_t)(r0 + ty + i * 4) * HID + (c0 + tx)];
    __syncthreads();
#pragma unroll
    for (int i = 0; i < 16; ++i)
      W2t[(size_t)(c0 + ty + i * 4) * FF + (r0 + tx)] =
          __float2bfloat16(tile[tx][ty + i * 4]);
    return;
  }

  // ---- T1 XCD-chunked decode (bijective: 4096 = 8 XCDs x 512) ----
  const int g = bid - NBT2;              // 0..4095; bid%8 alignment: 1024%8==0
  const int xcd = g & 7;
  const int j = g >> 3;                  // 0..511
  const int mt = (j & 15) * 8 + xcd;     // m-tile 0..127, ≡ xcd (mod 8)
  const int nt = j >> 4;                 // n-tile 0..31
  const int Mc = *cnt;
  const int m0 = mt * 128;
  if (m0 >= Mc) return;
  const int n0 = nt * 128;

  __hip_bfloat16* lA = (__hip_bfloat16*)smem;            // 16 KiB
  __hip_bfloat16* lB = (__hip_bfloat16*)(smem + 16384);  // 16 KiB

  const int wave = tid >> 6, lane = tid & 63;
  const int wr = (wave >> 1) * 64, wc = (wave & 1) * 64;
  const int fm = lane & 15, quad = lane >> 4;

  const int srow = (lane >> 3);                       // 0..7
  const int sg   = ((lane & 7) ^ srow) * 8;           // global elem offset

  f32x4 acc[4][4] = {};

  const __hip_bfloat16* gA = A  + (size_t)(m0 + wave * 32 + srow) * HID + sg;
  const __hip_bfloat16* gB = Bt + (size_t)(n0 + wave * 32 + srow) * HID + sg;
  char* dA = (char*)lA + wave * 4096;
  char* dB = (char*)lB + wave * 4096;

  for (int kt = 0; kt < HID; kt += 64) {
    __syncthreads();
#pragma unroll
    for (int c = 0; c < 4; ++c) {
      gload_lds16(gA + (size_t)(c * 8) * HID + kt, dA + c * 1024);
      gload_lds16(gB + (size_t)(c * 8) * HID + kt, dB + c * 1024);
    }
    __syncthreads();
#pragma unroll
    for (int ks = 0; ks < 2; ++ks) {
      bf16x8 af[4], bb[4];
#pragma unroll
      for (int i = 0; i < 4; ++i)
        af[i] = *(const bf16x8*)&lA[(wr + i * 16 + fm) * 64 + (((ks * 4 + quad) ^ (fm & 7)) * 8)];
#pragma unroll
      for (int j2 = 0; j2 < 4; ++j2)
        bb[j2] = *(const bf16x8*)&lB[(wc + j2 * 16 + fm) * 64 + (((ks * 4 + quad) ^ (fm & 7)) * 8)];
#pragma unroll
      for (int i = 0; i < 4; ++i)
#pragma unroll
        for (int j2 = 0; j2 < 4; ++j2)
          acc[i][j2] = __builtin_amdgcn_mfma_f32_16x16x32_bf16(af[i], bb[j2], acc[i][j2], 0, 0, 0);
    }
  }

#pragma unroll
  for (int j2 = 0; j2 < 4; ++j2) {
    const int col = n0 + wc + j2 * 16 + fm;
    const float bv = bias[col];
#pragma unroll
    for (int i = 0; i < 4; ++i) {
      const int rbase = m0 + wr + i * 16 + quad * 4;
#pragma unroll
      for (int r = 0; r < 4; ++r) {
        float v = acc[i][j2][r] + bv;
        v = v > 0.f ? v : 0.f;
        Act[(size_t)(rbase + r) * FF + col] = __float2bfloat16(v);
      }
    }
  }
}

// GEMM2: out[idx[m]] = Act @ W2t^T + b2, fp32 scatter. K=FF=4096.
// EXACT R6 version (106.8us plateau; 7 variants measured, all worse):
// BM=64 x BN=128, 4 waves x (32x64), single-buffered, ~1144 active blocks,
// 24 KiB LDS, 16x16 MFMA. No swizzle (resident set ~= whole grid).
__global__ __launch_bounds__(256, 4) void k_gemm2(const __hip_bfloat16* __restrict__ Act,
                                                  const __hip_bfloat16* __restrict__ Bt,
                                                  const float* __restrict__ bias,
                                                  const int* __restrict__ idx,
                                                  float* __restrict__ out,
                                                  const int* __restrict__ cnt) {
  const int Mc = *cnt;
  const int m0 = blockIdx.x * 64;
  if (m0 >= Mc) return;
  const int n0 = blockIdx.y * 128;

  __shared__ __hip_bfloat16 lA[64 * 64];   // 8 KiB
  __shared__ __hip_bfloat16 lB[128 * 64];  // 16 KiB

  const int tid = threadIdx.x;
  const int wave = tid >> 6, lane = tid & 63;
  const int wr = (wave >> 1) * 32, wc = (wave & 1) * 64;
  const int fm = lane & 15, quad = lane >> 4;
  const int srow = (lane >> 3);
  const int sg   = ((lane & 7) ^ srow) * 8;

  f32x4 acc[2][4] = {};

  const __hip_bfloat16* gA = Act + (size_t)(m0 + wave * 16 + srow) * FF + sg;
  const __hip_bfloat16* gB = Bt  + (size_t)(n0 + wave * 32 + srow) * FF + sg;
  char* dA = (char*)lA + wave * 2048;
  char* dB = (char*)lB + wave * 4096;

  for (int kt = 0; kt < FF; kt += 64) {
    __syncthreads();
#pragma unroll
    for (int c = 0; c < 2; ++c)
      gload_lds16(gA + (size_t)(c * 8) * FF + kt, dA + c * 1024);
#pragma unroll
    for (int c = 0; c < 4; ++c)
      gload_lds16(gB + (size_t)(c * 8) * FF + kt, dB + c * 1024);
    __syncthreads();
#pragma unroll
    for (int ks = 0; ks < 2; ++ks) {
      bf16x8 af[2], bb[4];
#pragma unroll
      for (int i = 0; i < 2; ++i)
        af[i] = *(const bf16x8*)&lA[(wr + i * 16 + fm) * 64 + (((ks * 4 + quad) ^ (fm & 7)) * 8)];
#pragma unroll
      for (int j = 0; j < 4; ++j)
        bb[j] = *(const bf16x8*)&lB[(wc + j * 16 + fm) * 64 + (((ks * 4 + quad) ^ (fm & 7)) * 8)];
#pragma unroll
      for (int i = 0; i < 2; ++i)
#pragma unroll
        for (int j = 0; j < 4; ++j)
          acc[i][j] = __builtin_amdgcn_mfma_f32_16x16x32_bf16(af[i], bb[j], acc[i][j], 0, 0, 0);
    }
  }

#pragma unroll
  for (int i = 0; i < 2; ++i) {
#pragma unroll
    for (int r = 0; r < 4; ++r) {
      const int m = m0 + wr + i * 16 + quad * 4 + r;
      if (m < Mc) {
        const int t = idx[m];
        float* orow = out + (size_t)t * HID + n0 + wc + fm;
#pragma unroll
        for (int j = 0; j < 4; ++j)
          orow[j * 16] = acc[i][j][r] + bias[n0 + wc + j * 16 + fm];
      }
    }
  }
}

// ---------------- launch ----------------
extern "C" void kernel_launch(void* const* d_in, const int* in_sizes, int n_in,
                              void* d_out, int out_size, void* d_ws, size_t ws_size,
                              hipStream_t stream) {
  const float* h   = (const float*)d_in[0];
  const float* Wg  = (const float*)d_in[3];
  const float* bg  = (const float*)d_in[4];
  const float* W1  = (const float*)d_in[5];
  const float* b1  = (const float*)d_in[6];
  const float* W2  = (const float*)d_in[7];
  const float* b2  = (const float*)d_in[8];
  const int*  labels = (const int*)d_in[9];
  float* out = (float*)d_out;

  char* ws = (char*)d_ws;
  int* cnt            = (int*)(ws + 0);
  int* idx            = (int*)(ws + 1024);
  __hip_bfloat16* W1t = (__hip_bfloat16*)(ws + (1u  << 17));   // [FF][HID]
  __hip_bfloat16* W2t = (__hip_bfloat16*)(ws + (16u << 20));   // [HID][FF]
  __hip_bfloat16* A   = (__hip_bfloat16*)(ws + (32u << 20));   // [TOK][HID]
  __hip_bfloat16* Act = (__hip_bfloat16*)(ws + (64ull << 20)); // [TOK][FF]

  hipMemsetAsync(cnt, 0, 4, stream);
  k_pre<<<NBT1 + TOK / GTOK, 256, 0, stream>>>(W1, W1t, h, Wg, bg, labels,
                                               out, A, idx, cnt);
  k_gemm1<<<NBT2 + (TOK / 128) * (FF / 128), 256, 0, stream>>>(A, W1t, b1, Act,
                                                               cnt, W2, W2t);
  k_gemm2<<<dim3(TOK / 64, HID / 128), 256, 0, stream>>>(Act, W2t, b2, idx, out, cnt);
}